// Round 10
// baseline (77.887 us; speedup 1.0000x reference)
//
#include <hip/hip_runtime.h>

typedef unsigned short u16;
typedef unsigned int   u32;
typedef float f32x4 __attribute__((ext_vector_type(4)));
typedef u16   u16x8 __attribute__((ext_vector_type(8)));
typedef short s16x8 __attribute__((ext_vector_type(8)));
typedef u32   u32x4 __attribute__((ext_vector_type(4)));

#define B_  8
#define S_  4096
#define D_  2048
#define E_  64
#define M_  (B_ * S_)
#define BM  16            // rows per block
#define BK  64
#define KHALF 1024        // per wave-pair K range
#define NT  (KHALF / BK)  // 16 k-tiles per half

__device__ __forceinline__ u16 f2bf(float f) {
  u32 u = __builtin_bit_cast(u32, f);
  u += 0x7fffu + ((u >> 16) & 1u);
  return (u16)(u >> 16);
}
__device__ __forceinline__ float bf2f(u16 h) {
  u32 u = ((u32)h) << 16;
  return __builtin_bit_cast(float, u);
}
__device__ __forceinline__ u32 cvtpk_bf16(float a, float b) {
  u32 r;
  asm("v_cvt_pk_bf16_f32 %0, %1, %2" : "=v"(r) : "v"(a), "v"(b));
  return r;
}

// split 8 consecutive f32 into hi/lo bf16 fragments (RNE hi, residual lo)
__device__ __forceinline__ void split8v(f32x4 f0, f32x4 f1, s16x8& hi, s16x8& lo) {
  u32x4 h, l;
  float fa[8] = {f0[0], f0[1], f0[2], f0[3], f1[0], f1[1], f1[2], f1[3]};
  #pragma unroll
  for (int j = 0; j < 4; ++j) {
    float a = fa[2 * j], b = fa[2 * j + 1];
    u32 hw = cvtpk_bf16(a, b);
    float ra = a - __builtin_bit_cast(float, hw << 16);
    float rb = b - __builtin_bit_cast(float, hw & 0xffff0000u);
    l[j] = cvtpk_bf16(ra, rb);
    h[j] = hw;
  }
  hi = __builtin_bit_cast(s16x8, h);
  lo = __builtin_bit_cast(s16x8, l);
}

__device__ __forceinline__ void gload16(const void* g, void* l) {
  __builtin_amdgcn_global_load_lds(
      (const __attribute__((address_space(1))) void*)g,
      (__attribute__((address_space(3))) void*)l, 16, 0, 0);
}
__device__ __forceinline__ f32x4 mfma16(s16x8 a, s16x8 b, f32x4 c) {
  return __builtin_amdgcn_mfma_f32_16x16x32_bf16(a, b, c, 0, 0, 0);
}

// ---------------- merged prep: blocks 0-7 compaction, blocks 8+ W conversion ----
__launch_bounds__(1024)
__global__ void prep_kernel(const float* __restrict__ W,
                            u16* __restrict__ whiT, u16* __restrict__ wloT,
                            const int* __restrict__ idxs,
                            int* __restrict__ compact, int* __restrict__ posmap,
                            int* __restrict__ count) {
  __shared__ u32 flag[S_];
  __shared__ int wtot[16], wpre[16];
  const int t = threadIdx.x;

  if (blockIdx.x >= 8) {
    int i = (blockIdx.x - 8) * 1024 + t;   // 0 .. D*E-1
    int k = i >> 6;
    int e = i & 63;
    float w = W[i];
    u16 h = f2bf(w);
    u16 l = f2bf(w - bf2f(h));
    whiT[(size_t)e * D_ + k] = h;
    wloT[(size_t)e * D_ + k] = l;
    return;
  }

  const int b = blockIdx.x;
  const int lane = t & 63, wid = t >> 6;

  #pragma unroll
  for (int j = 0; j < 4; ++j) flag[t + j * 1024] = 0;
  __syncthreads();
  #pragma unroll
  for (int j = 0; j < 4; ++j) flag[idxs[b * S_ + t + j * 1024]] = 1;
  __syncthreads();

  int f[4], s = 0;
  #pragma unroll
  for (int j = 0; j < 4; ++j) { f[j] = (int)flag[t * 4 + j]; s += f[j]; }
  int inc = s;
  #pragma unroll
  for (int off = 1; off < 64; off <<= 1) {
    int v = __shfl_up(inc, off);
    if (lane >= off) inc += v;
  }
  if (lane == 63) wtot[wid] = inc;
  __syncthreads();
  if (t == 0) {
    int acc = 0;
    for (int w = 0; w < 16; ++w) { wpre[w] = acc; acc += wtot[w]; }
    count[b] = acc;
  }
  __syncthreads();
  int p = wpre[wid] + inc - s;
  #pragma unroll
  for (int j = 0; j < 4; ++j) {
    int g = t * 4 + j;
    if (f[j]) {
      compact[b * S_ + p] = g;
      posmap[b * S_ + g] = p;
      ++p;
    }
  }
}

// ---- fused GEMM + topk: BM=16, 4 waves = {K-half} x {expert-half} ----
// Wave w: half = w>>1 (K in [half*1024,(half+1)*1024)), esel = w&1 (experts
// [esel*32, esel*32+32)). All waves cover the same 16 rows. R9-proven loop:
// gload_lds staging + plain __syncthreads, XOR-swizzled LDS. 40 KB -> 4 blk/CU.
__launch_bounds__(256)
__global__ void fused_gemm_topk(const float* __restrict__ A,      // [8][4096][2048]
                                const u16* __restrict__ WhiT,     // [64][2048]
                                const u16* __restrict__ WloT,
                                const int* __restrict__ compact,  // [8][4096]
                                const int* __restrict__ count,    // [8]
                                float* __restrict__ mask) {       // [8][4096][64]
  __shared__ __align__(16) float Ah[2][BM * BK];     // 2 x 4 KB (XOR-swizzled)
  __shared__ __align__(16) u16  Whs[2][E_ * BK];     // 2 x 8 KB
  __shared__ __align__(16) u16  Wls[2][E_ * BK];     // 2 x 8 KB

  const int b    = blockIdx.x >> 8;      // 8 batches x 256 tiles
  const int tile = blockIdx.x & 255;
  const int row0 = tile * BM;
  const int cnt  = count[b];
  if (row0 >= cnt) return;

  const int t    = threadIdx.x;
  const int lane = t & 63;
  const int wid  = t >> 6;
  const int fr   = lane & 15;
  const int fk   = lane >> 4;            // 0..3 (k-subgroup)
  const int half = t >> 7;               // 0: waves {0,1}, 1: waves {2,3}
  const int esel = wid & 1;              // expert half within the K-half pair
  const int pt   = t & 127;
  const int kbeg = half * KHALF;

  // --- A staging sources (pre-swizzled global addr; LDS dest linear) ---
  // A tile 16 rows x 256 B: slot = s*128+pt, row = slot>>4, l = (slot&15)^(row&7)
  const float* asrc[2];
  #pragma unroll
  for (int s = 0; s < 2; ++s) {
    int slot = s * 128 + pt;
    int row  = slot >> 4;
    int l    = (slot & 15) ^ (row & 7);
    int rr   = row0 + row; if (rr >= cnt) rr = cnt - 1;
    int grow = compact[b * S_ + rr];
    asrc[s] = A + ((size_t)b * S_ + grow) * D_ + kbeg + l * 4;
  }
  // --- W staging sources: e-row = 128B = 8 slots; l = (slot&7) ^ (e&7) ---
  const u16* whsrc[4];
  const u16* wlsrc[4];
  #pragma unroll
  for (int s = 0; s < 4; ++s) {
    int slot = s * 128 + pt;
    int e    = slot >> 3;
    int l    = (slot & 7) ^ (e & 7);
    whsrc[s] = WhiT + (size_t)e * D_ + kbeg + l * 8;
    wlsrc[s] = WloT + (size_t)e * D_ + kbeg + l * 8;
  }

  // --- LDS read byte offsets (swizzled), static across k-iters ---
  const int arow = fr;                   // 16 rows, all waves
  const int axr  = (arow & 7) << 4;
  u32 aoff[2][2];
  #pragma unroll
  for (int ks = 0; ks < 2; ++ks) {
    aoff[ks][0] = arow * 256 + ((ks * 128 + fk * 32) ^ axr);
    aoff[ks][1] = arow * 256 + ((ks * 128 + fk * 32 + 16) ^ axr);
  }
  u32 woff[2][2];
  #pragma unroll
  for (int n = 0; n < 2; ++n) {
    int e  = esel * 32 + n * 16 + fr;
    int xe = (e & 7) << 4;
    #pragma unroll
    for (int ks = 0; ks < 2; ++ks)
      woff[ks][n] = e * 128 + ((ks * 64 + fk * 16) ^ xe);
  }

  f32x4 acc[2] = {};
  const char* aL = (const char*)Ah[half];
  const char* hL = (const char*)Whs[half];
  const char* lL = (const char*)Wls[half];

  for (int tt = 0; tt < NT; ++tt) {
    const int koff = tt * BK;
    // stage this half's tile (single buffer; prior compute done at tail barrier)
    #pragma unroll
    for (int s = 0; s < 2; ++s)
      gload16(asrc[s] + koff, (char*)Ah[half] + (size_t)(s * 128 + pt) * 16);
    #pragma unroll
    for (int s = 0; s < 4; ++s) {
      gload16(whsrc[s] + koff, (char*)Whs[half] + (size_t)(s * 128 + pt) * 16);
      gload16(wlsrc[s] + koff, (char*)Wls[half] + (size_t)(s * 128 + pt) * 16);
    }
    __syncthreads();   // compiler drains vmcnt(0) before s_barrier

    #pragma unroll
    for (int ks = 0; ks < 2; ++ks) {
      f32x4 af0 = *(const f32x4*)(aL + aoff[ks][0]);
      f32x4 af1 = *(const f32x4*)(aL + aoff[ks][1]);
      s16x8 ah, al;
      split8v(af0, af1, ah, al);
      #pragma unroll
      for (int n = 0; n < 2; ++n) {
        s16x8 wh = *(const s16x8*)(hL + woff[ks][n]);
        s16x8 wl = *(const s16x8*)(lL + woff[ks][n]);
        acc[n] = mfma16(al, wh, acc[n]);
        acc[n] = mfma16(ah, wl, acc[n]);
        acc[n] = mfma16(ah, wh, acc[n]);
      }
    }
    __syncthreads();
  }

  // ---- cross-wave reduce via LDS (reuse Ah: 8 KB = Pr[2][64][16] f32) ----
  // C/D layout: col = esel*32 + n*16 + fr, local row = (lane>>4)*4 + r.
  // Pr column-major [half][col][row] so acc's 4 regs store as one f32x4.
  float* Pr = &Ah[0][0];
  #pragma unroll
  for (int n = 0; n < 2; ++n) {
    int col = esel * 32 + n * 16 + fr;
    *(f32x4*)&Pr[half * 1024 + col * 16 + (lane >> 4) * 4] = acc[n];
  }
  __syncthreads();

  if (wid == 0) {
    // sum halves: sum[n][r] = logit[row=(lane>>4)*4+r][col=n*16+fr]
    f32x4 sum[4];
    #pragma unroll
    for (int n = 0; n < 4; ++n) {
      int col = n * 16 + fr;
      f32x4 v0 = *(const f32x4*)&Pr[col * 16 + (lane >> 4) * 4];
      f32x4 v1 = *(const f32x4*)&Pr[1024 + col * 16 + (lane >> 4) * 4];
      sum[n] = v0 + v1;   // half0 + half1 (same order as R9)
    }

    // per-row top-4 + softmax over 16-lane groups (R9-verified logic)
    #pragma unroll
    for (int r = 0; r < 4; ++r) {
      float rv[4]; int ri[4];
      #pragma unroll
      for (int n = 0; n < 4; ++n) { rv[n] = sum[n][r]; ri[n] = n * 16 + fr; }
      float vals[4]; int inds[4];
      #pragma unroll
      for (int tk = 0; tk < 4; ++tk) {
        float mv = rv[0]; int mi = ri[0];
        #pragma unroll
        for (int n = 1; n < 4; ++n)
          if (rv[n] > mv || (rv[n] == mv && ri[n] < mi)) { mv = rv[n]; mi = ri[n]; }
        #pragma unroll
        for (int off = 8; off > 0; off >>= 1) {     // reduce within 16-lane group
          float ov = __shfl_xor(mv, off);
          int   oi = __shfl_xor(mi, off);
          if (ov > mv || (ov == mv && oi < mi)) { mv = ov; mi = oi; }  // tie->smaller idx
        }
        vals[tk] = mv; inds[tk] = mi;
        #pragma unroll
        for (int n = 0; n < 4; ++n) if (ri[n] == mi) rv[n] = -INFINITY;
      }
      float w[4], ssum = 0.f;
      #pragma unroll
      for (int tk = 0; tk < 4; ++tk) { w[tk] = __expf(vals[tk] - vals[0]); ssum += w[tk]; }
      float inv = 1.f / ssum;

      int mrow = row0 + (lane >> 4) * 4 + r;
      float* mr = mask + ((size_t)b * S_ + mrow) * E_;
      #pragma unroll
      for (int n = 0; n < 4; ++n) {
        int col = n * 16 + fr;
        float o = 0.f;
        #pragma unroll
        for (int tk = 0; tk < 4; ++tk) if (col == inds[tk]) o = w[tk] * inv;
        mr[col] = o;
      }
    }
  }
}

// ---------------- scatter: out[r] = mask[b][posmap[idxs[r]]] ----------------
__launch_bounds__(256)
__global__ void scatter_kernel(const float* __restrict__ mask,   // [8][4096][64]
                               const int* __restrict__ idxs,     // [8][4096]
                               const int* __restrict__ posmap,   // [8][4096]
                               float* __restrict__ out) {        // [8][4096][64]
  const int lane = threadIdx.x & 63;
  const int wid  = threadIdx.x >> 6;
  const int r    = blockIdx.x * 4 + wid;
  const int b    = r >> 12;
  const int p    = posmap[(size_t)b * S_ + idxs[r]];
  out[(size_t)r * E_ + lane] = mask[((size_t)b * S_ + p) * E_ + lane];
}

// ---------------- host ----------------
extern "C" void kernel_launch(void* const* d_in, const int* in_sizes, int n_in,
                              void* d_out, int out_size, void* d_ws, size_t ws_size,
                              hipStream_t stream) {
  const float* hidden = (const float*)d_in[0];
  const int*   idxs   = (const int*)d_in[1];
  const float* W      = (const float*)d_in[2];
  float* out = (float*)d_out;

  // ws: mask (8MB) | WhiT (256KB) | WloT (256KB) | compact (128KB) | posmap (128KB) | count
  char* wsp = (char*)d_ws;
  float* mask = (float*)wsp;                     wsp += (size_t)M_ * E_ * 4;
  u16* whiT = (u16*)wsp;                         wsp += (size_t)E_ * D_ * 2;
  u16* wloT = (u16*)wsp;                         wsp += (size_t)E_ * D_ * 2;
  int* compact = (int*)wsp;                      wsp += (size_t)M_ * 4;
  int* posmap  = (int*)wsp;                      wsp += (size_t)M_ * 4;
  int* count   = (int*)wsp;

  prep_kernel<<<8 + (D_ * E_) / 1024, 1024, 0, stream>>>(W, whiT, wloT, idxs,
                                                          compact, posmap, count);
  fused_gemm_topk<<<B_ * 256, 256, 0, stream>>>(hidden, whiT, wloT, compact, count, mask);
  scatter_kernel<<<M_ / 4, 256, 0, stream>>>(mask, idxs, posmap, out);
}

// Round 11
// 56.259 us; speedup vs baseline: 1.3844x; 1.3844x over previous
//
#include <hip/hip_runtime.h>

typedef unsigned short u16;
typedef unsigned int   u32;
typedef float f32x4 __attribute__((ext_vector_type(4)));
typedef u16   u16x8 __attribute__((ext_vector_type(8)));
typedef short s16x8 __attribute__((ext_vector_type(8)));
typedef u32   u32x4 __attribute__((ext_vector_type(4)));

#define B_  8
#define S_  4096
#define D_  2048
#define E_  64
#define M_  (B_ * S_)
#define BM  32            // rows per block (R9-proven)
#define BK  64
#define KHALF 1024        // per wave-pair K range
#define NT  (KHALF / BK)  // 16 k-tiles per half

__device__ __forceinline__ u16 f2bf(float f) {
  u32 u = __builtin_bit_cast(u32, f);
  u += 0x7fffu + ((u >> 16) & 1u);
  return (u16)(u >> 16);
}
__device__ __forceinline__ float bf2f(u16 h) {
  u32 u = ((u32)h) << 16;
  return __builtin_bit_cast(float, u);
}
__device__ __forceinline__ u32 cvtpk_bf16(float a, float b) {
  u32 r;
  asm("v_cvt_pk_bf16_f32 %0, %1, %2" : "=v"(r) : "v"(a), "v"(b));
  return r;
}

// split 8 consecutive f32 into hi/lo bf16 fragments (RNE hi, residual lo)
__device__ __forceinline__ void split8v(f32x4 f0, f32x4 f1, s16x8& hi, s16x8& lo) {
  u32x4 h, l;
  float fa[8] = {f0[0], f0[1], f0[2], f0[3], f1[0], f1[1], f1[2], f1[3]};
  #pragma unroll
  for (int j = 0; j < 4; ++j) {
    float a = fa[2 * j], b = fa[2 * j + 1];
    u32 hw = cvtpk_bf16(a, b);
    float ra = a - __builtin_bit_cast(float, hw << 16);
    float rb = b - __builtin_bit_cast(float, hw & 0xffff0000u);
    l[j] = cvtpk_bf16(ra, rb);
    h[j] = hw;
  }
  hi = __builtin_bit_cast(s16x8, h);
  lo = __builtin_bit_cast(s16x8, l);
}

__device__ __forceinline__ void gload16(const void* g, void* l) {
  __builtin_amdgcn_global_load_lds(
      (const __attribute__((address_space(1))) void*)g,
      (__attribute__((address_space(3))) void*)l, 16, 0, 0);
}
__device__ __forceinline__ f32x4 mfma16(s16x8 a, s16x8 b, f32x4 c) {
  return __builtin_amdgcn_mfma_f32_16x16x32_bf16(a, b, c, 0, 0, 0);
}

// ---- merged prep ----
// blocks 0-7: per-batch compaction + CSR (off/csr) build
// blocks 8-39: W [D][E] -> hi/lo bf16 transposed [E][D], coalesced via LDS transpose
__launch_bounds__(1024)
__global__ void prep_kernel(const float* __restrict__ W,
                            u16* __restrict__ whiT, u16* __restrict__ wloT,
                            const int* __restrict__ idxs,
                            int* __restrict__ compact,   // [8][4096]
                            u32* __restrict__ off,       // [8][4097]
                            int* __restrict__ csr,       // [8][4096]
                            int* __restrict__ count) {   // [8]
  const int t = threadIdx.x;

  if (blockIdx.x >= 8) {
    // ---- convert: 64k x 64e tile, coalesced read + coalesced write ----
    __shared__ float tile[64][65];
    const int k0 = (blockIdx.x - 8) * 64;
    #pragma unroll
    for (int q = 0; q < 4; ++q) {
      int kk = q * 16 + (t >> 6);
      int e  = t & 63;
      tile[kk][e] = W[(size_t)(k0 + kk) * E_ + e];   // 256B coalesced per wave
    }
    __syncthreads();
    #pragma unroll
    for (int q = 0; q < 4; ++q) {
      int e  = q * 16 + (t >> 6);
      int kk = t & 63;
      float w = tile[kk][e];
      u16 h = f2bf(w);
      u16 l = f2bf(w - bf2f(h));
      whiT[(size_t)e * D_ + k0 + kk] = h;            // 128B coalesced per wave
      wloT[(size_t)e * D_ + k0 + kk] = l;
    }
    return;
  }

  // ---- per-batch compaction + CSR ----
  __shared__ u32 flag[S_];       // flags -> hist -> fill counters
  __shared__ u16 plds[S_];       // posmap (LDS copy)
  __shared__ u32 offl[S_ + 1];   // exclusive offsets
  __shared__ int wtot[16], wpre[16];

  const int b = blockIdx.x;
  const int lane = t & 63, wv = t >> 6;

  // phase 1: presence flags
  #pragma unroll
  for (int j = 0; j < 4; ++j) flag[t + j * 1024] = 0;
  __syncthreads();
  #pragma unroll
  for (int j = 0; j < 4; ++j) flag[idxs[b * S_ + t + j * 1024]] = 1;
  __syncthreads();

  // phase 2: scan flags -> compact + plds + count
  {
    int f[4], s = 0;
    #pragma unroll
    for (int j = 0; j < 4; ++j) { f[j] = (int)flag[t * 4 + j]; s += f[j]; }
    int inc = s;
    #pragma unroll
    for (int o = 1; o < 64; o <<= 1) {
      int v = __shfl_up(inc, o);
      if (lane >= o) inc += v;
    }
    if (lane == 63) wtot[wv] = inc;
    __syncthreads();
    if (t == 0) {
      int acc = 0;
      for (int w = 0; w < 16; ++w) { wpre[w] = acc; acc += wtot[w]; }
      count[b] = acc;
    }
    __syncthreads();
    int p = wpre[wv] + inc - s;
    #pragma unroll
    for (int j = 0; j < 4; ++j) {
      int g = t * 4 + j;
      if (f[j]) {
        compact[b * S_ + p] = g;
        plds[g] = (u16)p;
        ++p;
      }
    }
  }
  __syncthreads();

  // phase 3: histogram of p over output rows (reuse flag)
  #pragma unroll
  for (int j = 0; j < 4; ++j) flag[t + j * 1024] = 0;
  __syncthreads();
  #pragma unroll
  for (int j = 0; j < 4; ++j) {
    int r = t + j * 1024;
    int p = plds[idxs[b * S_ + r]];
    atomicAdd(&flag[p], 1u);
  }
  __syncthreads();

  // phase 4: exclusive scan of hist -> offl, write to global off
  {
    int h[4], s2 = 0;
    #pragma unroll
    for (int j = 0; j < 4; ++j) { h[j] = (int)flag[t * 4 + j]; s2 += h[j]; }
    int inc2 = s2;
    #pragma unroll
    for (int o = 1; o < 64; o <<= 1) {
      int v = __shfl_up(inc2, o);
      if (lane >= o) inc2 += v;
    }
    if (lane == 63) wtot[wv] = inc2;
    __syncthreads();
    if (t == 0) {
      int acc = 0;
      for (int w = 0; w < 16; ++w) { wpre[w] = acc; acc += wtot[w]; }
    }
    __syncthreads();
    u32 e0 = (u32)(wpre[wv] + inc2 - s2);
    #pragma unroll
    for (int j = 0; j < 4; ++j) { offl[t * 4 + j] = e0; e0 += (u32)h[j]; }
    if (t == 1023) offl[S_] = e0;   // = 4096
  }
  __syncthreads();
  #pragma unroll
  for (int j = 0; j < 4; ++j)
    off[b * (S_ + 1) + t + j * 1024] = offl[t + j * 1024];
  if (t == 0) off[b * (S_ + 1) + S_] = offl[S_];

  // phase 5: fill csr (reuse flag as per-p fill counters)
  #pragma unroll
  for (int j = 0; j < 4; ++j) flag[t + j * 1024] = 0;
  __syncthreads();
  #pragma unroll
  for (int j = 0; j < 4; ++j) {
    int r = t + j * 1024;
    int p = plds[idxs[b * S_ + r]];
    u32 slot = offl[p] + atomicAdd(&flag[p], 1u);
    csr[b * S_ + slot] = r;
  }
}

// ---- fused GEMM (+in-block K-split) + cross-half reduce + top-4 + softmax ----
// R9-proven loop (byte-identical): BM=32, waves {0,1} K[0,1024), {2,3} K[1024,2048),
// gload_lds staging, plain __syncthreads, XOR-swizzled LDS.
// Epilogue: CSR direct write of duplicates to out (replaces mask+scatter).
__launch_bounds__(256)
__global__ void fused_gemm_topk(const float* __restrict__ A,      // [8][4096][2048]
                                const u16* __restrict__ WhiT,     // [64][2048]
                                const u16* __restrict__ WloT,
                                const int* __restrict__ compact,  // [8][4096]
                                const int* __restrict__ count,    // [8]
                                const u32* __restrict__ off,      // [8][4097]
                                const int* __restrict__ csr,      // [8][4096]
                                float* __restrict__ out) {        // [8][4096][64]
  __shared__ __align__(16) float Ah[2][BM * BK];     // 2 x 8 KB (XOR-swizzled)
  __shared__ __align__(16) u16  Whs[2][E_ * BK];     // 2 x 8 KB
  __shared__ __align__(16) u16  Wls[2][E_ * BK];     // 2 x 8 KB

  const int b    = blockIdx.x >> 7;      // 8 batches x 128 tiles
  const int tile = blockIdx.x & 127;
  const int row0 = tile * BM;
  const int cnt  = count[b];
  if (row0 >= cnt) return;

  const int t    = threadIdx.x;
  const int lane = t & 63;
  const int wid  = t >> 6;
  const int fr   = lane & 15;
  const int fk   = lane >> 4;            // 0..3 (k-subgroup)
  const int half = t >> 7;               // 0: waves {0,1}, 1: waves {2,3}
  const int pt   = t & 127;
  const int kbeg = half * KHALF;

  // --- A staging sources (pre-swizzled global addr; LDS dest linear) ---
  const float* asrc[4];
  #pragma unroll
  for (int s = 0; s < 4; ++s) {
    int slot = s * 128 + pt;
    int row  = slot >> 4;
    int l    = (slot & 15) ^ (row & 7);
    int rr   = row0 + row; if (rr >= cnt) rr = cnt - 1;
    int grow = compact[b * S_ + rr];
    asrc[s] = A + ((size_t)b * S_ + grow) * D_ + kbeg + l * 4;
  }
  // --- W staging sources: e-row = 128B = 8 slots; l = (slot&7) ^ (e&7) ---
  const u16* whsrc[4];
  const u16* wlsrc[4];
  #pragma unroll
  for (int s = 0; s < 4; ++s) {
    int slot = s * 128 + pt;
    int e    = slot >> 3;
    int l    = (slot & 7) ^ (e & 7);
    whsrc[s] = WhiT + (size_t)e * D_ + kbeg + l * 8;
    wlsrc[s] = WloT + (size_t)e * D_ + kbeg + l * 8;
  }

  // --- LDS read byte offsets (swizzled), static across k-iters ---
  const int arow = (wid & 1) * 16 + fr;
  const int axr  = (arow & 7) << 4;
  u32 aoff[2][2];
  #pragma unroll
  for (int ks = 0; ks < 2; ++ks) {
    aoff[ks][0] = arow * 256 + ((ks * 128 + fk * 32) ^ axr);
    aoff[ks][1] = arow * 256 + ((ks * 128 + fk * 32 + 16) ^ axr);
  }
  u32 woff[2][4];
  #pragma unroll
  for (int n = 0; n < 4; ++n) {
    int e  = n * 16 + fr;
    int xe = (e & 7) << 4;
    #pragma unroll
    for (int ks = 0; ks < 2; ++ks)
      woff[ks][n] = e * 128 + ((ks * 64 + fk * 16) ^ xe);
  }

  f32x4 acc[4] = {};
  const char* aL = (const char*)Ah[half];
  const char* hL = (const char*)Whs[half];
  const char* lL = (const char*)Wls[half];

  for (int tt = 0; tt < NT; ++tt) {
    const int koff = tt * BK;
    #pragma unroll
    for (int s = 0; s < 4; ++s)
      gload16(asrc[s] + koff, (char*)Ah[half] + (size_t)(s * 128 + pt) * 16);
    #pragma unroll
    for (int s = 0; s < 4; ++s) {
      gload16(whsrc[s] + koff, (char*)Whs[half] + (size_t)(s * 128 + pt) * 16);
      gload16(wlsrc[s] + koff, (char*)Wls[half] + (size_t)(s * 128 + pt) * 16);
    }
    __syncthreads();   // compiler drains vmcnt(0) before s_barrier

    #pragma unroll
    for (int ks = 0; ks < 2; ++ks) {
      f32x4 af0 = *(const f32x4*)(aL + aoff[ks][0]);
      f32x4 af1 = *(const f32x4*)(aL + aoff[ks][1]);
      s16x8 ah, al;
      split8v(af0, af1, ah, al);
      #pragma unroll
      for (int n = 0; n < 4; ++n) {
        s16x8 wh = *(const s16x8*)(hL + woff[ks][n]);
        s16x8 wl = *(const s16x8*)(lL + woff[ks][n]);
        acc[n] = mfma16(al, wh, acc[n]);
        acc[n] = mfma16(ah, wl, acc[n]);
        acc[n] = mfma16(ah, wh, acc[n]);
      }
    }
    __syncthreads();
  }

  // ---- cross-half reduce: waves 2,3 -> LDS, waves 0,1 add (R9-verified) ----
  float* Pr = &Ah[0][0];   // 8 KB scratch, safe after final barrier
  if (wid >= 2) {
    #pragma unroll
    for (int n = 0; n < 4; ++n)
      #pragma unroll
      for (int r = 0; r < 4; ++r)
        Pr[(wid & 1) * 1024 + ((lane >> 4) * 4 + r) * 64 + n * 16 + fr] = acc[n][r];
  }
  __syncthreads();
  if (wid < 2) {
    #pragma unroll
    for (int n = 0; n < 4; ++n)
      #pragma unroll
      for (int r = 0; r < 4; ++r)
        acc[n][r] += Pr[wid * 1024 + ((lane >> 4) * 4 + r) * 64 + n * 16 + fr];

    // ---- per-row top-4 + softmax (R9-verified), then CSR duplicate writes ----
    #pragma unroll
    for (int r = 0; r < 4; ++r) {
      float rv[4]; int ri[4];
      #pragma unroll
      for (int n = 0; n < 4; ++n) { rv[n] = acc[n][r]; ri[n] = n * 16 + fr; }
      float vals[4]; int inds[4];
      #pragma unroll
      for (int tk = 0; tk < 4; ++tk) {
        float mv = rv[0]; int mi = ri[0];
        #pragma unroll
        for (int n = 1; n < 4; ++n)
          if (rv[n] > mv || (rv[n] == mv && ri[n] < mi)) { mv = rv[n]; mi = ri[n]; }
        #pragma unroll
        for (int o = 8; o > 0; o >>= 1) {           // reduce within 16-lane group
          float ov = __shfl_xor(mv, o);
          int   oi = __shfl_xor(mi, o);
          if (ov > mv || (ov == mv && oi < mi)) { mv = ov; mi = oi; }  // tie->smaller
        }
        vals[tk] = mv; inds[tk] = mi;
        #pragma unroll
        for (int n = 0; n < 4; ++n) if (ri[n] == mi) rv[n] = -INFINITY;
      }
      float w[4], ssum = 0.f;
      #pragma unroll
      for (int tk = 0; tk < 4; ++tk) { w[tk] = __expf(vals[tk] - vals[0]); ssum += w[tk]; }
      float inv = 1.f / ssum;

      // this lane's 4 output values (cols n*16+fr)
      float o4[4];
      #pragma unroll
      for (int n = 0; n < 4; ++n) {
        int col = n * 16 + fr;
        float o = 0.f;
        #pragma unroll
        for (int tk = 0; tk < 4; ++tk) if (col == inds[tk]) o = w[tk] * inv;
        o4[n] = o;
      }

      // duplicate writes: unique row p -> all output rows csr[off[p]..off[p+1])
      int p = row0 + wid * 16 + (lane >> 4) * 4 + r;
      u32 j0 = off[b * (S_ + 1) + p];
      u32 j1 = off[b * (S_ + 1) + p + 1];     // empty range for padding rows (p>=cnt)
      for (u32 j = j0; j < j1; ++j) {
        int orow = csr[b * S_ + j];
        float* mr = out + ((size_t)b * S_ + orow) * E_;
        #pragma unroll
        for (int n = 0; n < 4; ++n) mr[n * 16 + fr] = o4[n];
      }
    }
  }
}

// ---------------- host ----------------
extern "C" void kernel_launch(void* const* d_in, const int* in_sizes, int n_in,
                              void* d_out, int out_size, void* d_ws, size_t ws_size,
                              hipStream_t stream) {
  const float* hidden = (const float*)d_in[0];
  const int*   idxs   = (const int*)d_in[1];
  const float* W      = (const float*)d_in[2];
  float* out = (float*)d_out;

  // ws: WhiT (256KB) | WloT (256KB) | compact (128KB) | off (131KB) | csr (128KB) | count
  char* wsp = (char*)d_ws;
  u16* whiT = (u16*)wsp;                         wsp += (size_t)E_ * D_ * 2;
  u16* wloT = (u16*)wsp;                         wsp += (size_t)E_ * D_ * 2;
  int* compact = (int*)wsp;                      wsp += (size_t)M_ * 4;
  u32* off     = (u32*)wsp;                      wsp += (size_t)B_ * (S_ + 1) * 4;
  int* csr     = (int*)wsp;                      wsp += (size_t)M_ * 4;
  int* count   = (int*)wsp;

  prep_kernel<<<8 + D_ / 64, 1024, 0, stream>>>(W, whiT, wloT, idxs,
                                                 compact, off, csr, count);
  fused_gemm_topk<<<B_ * 128, 256, 0, stream>>>(hidden, whiT, wloT, compact, count,
                                                 off, csr, out);
}